// Round 1
// baseline (637.641 us; speedup 1.0000x reference)
//
#include <hip/hip_runtime.h>

#define N_NODES 8192
#define N_EDGES 4096
#define F_INS   256
#define HEADS   8
#define DOUT    64
#define HDIM    512   // HEADS*DOUT
#define CCOMB   1024  // 2*HDIM (both batches as columns)
#define BATCH   2

typedef __bf16 bf16x8 __attribute__((ext_vector_type(8)));
typedef __bf16 bf16x4 __attribute__((ext_vector_type(4)));
typedef float  f32x4  __attribute__((ext_vector_type(4)));

// ---------- H (fp32 N x E) -> Hb (bf16 N x E) and HbT (bf16 E x N) ----------
__launch_bounds__(256)
__global__ void convert_H_kernel(const float* __restrict__ H,
                                 __bf16* __restrict__ Hb,
                                 __bf16* __restrict__ HbT) {
    __shared__ __bf16 tile[32][33];
    int e0 = blockIdx.x * 32, n0 = blockIdx.y * 32;
    int t = threadIdx.x;
    int c = t & 31, r0 = t >> 5;
#pragma unroll
    for (int p = 0; p < 4; ++p) {
        int r = p * 8 + r0;
        float v = H[(size_t)(n0 + r) * N_EDGES + e0 + c];
        __bf16 bv = (__bf16)v;
        Hb[(size_t)(n0 + r) * N_EDGES + e0 + c] = bv;
        tile[r][c] = bv;
    }
    __syncthreads();
#pragma unroll
    for (int p = 0; p < 4; ++p) {
        int er = p * 8 + r0;
        HbT[(size_t)(e0 + er) * N_NODES + n0 + c] = tile[c][er];
    }
}

// ---------- x fp32 -> bf16 (vectorized) ----------
__launch_bounds__(256)
__global__ void cvt_x_kernel(const float* __restrict__ src, __bf16* __restrict__ dst, int n4) {
    int i = blockIdx.x * 256 + threadIdx.x;
    if (i >= n4) return;
    float4 v = ((const float4*)src)[i];
    bf16x4 o;
    o.x = (__bf16)v.x; o.y = (__bf16)v.y; o.z = (__bf16)v.z; o.w = (__bf16)v.w;
    ((bf16x4*)dst)[i] = o;
}

// ---------- W (fp32 F_INS x HDIM) -> WbT (bf16 HDIM x F_INS) ----------
__launch_bounds__(256)
__global__ void wbt_kernel(const float* __restrict__ W, __bf16* __restrict__ WbT) {
    int i = blockIdx.x * 256 + threadIdx.x;  // 512*256 = 131072
    int c = i >> 8, f = i & 255;
    WbT[i] = (__bf16)W[(size_t)f * HDIM + c];
}

// ---------- Wa[f][h] = sum_d W[f][h*64+d] * a[d]  (fp32, exact path for av) ----------
__launch_bounds__(256)
__global__ void wa_kernel(const float* __restrict__ W, const float* __restrict__ a,
                          float* __restrict__ Wa) {
    int i = blockIdx.x * 256 + threadIdx.x;  // 2048
    if (i >= F_INS * HEADS) return;
    int f = i >> 3, h = i & 7;
    float s = 0.f;
#pragma unroll 8
    for (int d = 0; d < DOUT; ++d) s += W[(size_t)f * HDIM + h * DOUT + d] * a[d];
    Wa[i] = s;
}

// ---------- av[b,n,h] = leaky_relu( x[b,n,:] . Wa[:,h] )  fully fp32 ----------
__launch_bounds__(256)
__global__ void av_kernel(const float* __restrict__ x, const float* __restrict__ Wa,
                          float* __restrict__ av) {
    __shared__ float lx[32][257];
    __shared__ float lwa[F_INS * HEADS];
    int t = threadIdx.x;
    size_t row0 = (size_t)blockIdx.x * 32;  // rows = b*8192+n, 16384 total
    for (int p = t; p < F_INS * HEADS; p += 256) lwa[p] = Wa[p];
#pragma unroll
    for (int p = 0; p < 32; ++p) lx[p][t] = x[(row0 + p) * F_INS + t];
    __syncthreads();
    int r = t >> 3, h = t & 7;
    float acc = 0.f;
#pragma unroll 8
    for (int f = 0; f < F_INS; ++f) acc += lx[r][f] * lwa[f * 8 + h];
    av[(row0 + r) * 8 + h] = acc > 0.f ? acc : 0.2f * acc;
}

// ---------- logits[bh][e] += sum over n-chunk of H[n,e]*av[b,n,h]  (fp32) ----------
__launch_bounds__(256)
__global__ void logits_kernel(const float* __restrict__ H, const float* __restrict__ av,
                              float* __restrict__ logits) {
    __shared__ float lav[512 * 16];
    int t = threadIdx.x;
    int e = blockIdx.x * 256 + t;
    int n0 = blockIdx.y * 512;
    for (int p = t; p < 8192; p += 256) {
        int b = p >> 12, rem = p & 4095, i = rem >> 3, h = rem & 7;
        lav[i * 16 + b * 8 + h] = av[(size_t)b * (N_NODES * 8) + (size_t)(n0 + i) * 8 + h];
    }
    __syncthreads();
    float acc[16];
#pragma unroll
    for (int bh = 0; bh < 16; ++bh) acc[bh] = 0.f;
    for (int i = 0; i < 512; ++i) {
        float hv = H[(size_t)(n0 + i) * N_EDGES + e];
#pragma unroll
        for (int bh = 0; bh < 16; ++bh) acc[bh] += hv * lav[i * 16 + bh];
    }
#pragma unroll
    for (int bh = 0; bh < 16; ++bh)
        atomicAdd(&logits[(size_t)bh * N_EDGES + e], acc[bh]);
}

// ---------- softmax over e for each of 16 (b,h) rows, in place ----------
__launch_bounds__(256)
__global__ void softmax_kernel(float* __restrict__ logits) {
    __shared__ float red[4];
    __shared__ float reds[4];
    int t = threadIdx.x;
    float* row = logits + (size_t)blockIdx.x * N_EDGES;
    float mx = -1e30f;
    for (int i = t; i < N_EDGES; i += 256) mx = fmaxf(mx, row[i]);
#pragma unroll
    for (int o = 32; o > 0; o >>= 1) mx = fmaxf(mx, __shfl_xor(mx, o, 64));
    if ((t & 63) == 0) red[t >> 6] = mx;
    __syncthreads();
    mx = fmaxf(fmaxf(red[0], red[1]), fmaxf(red[2], red[3]));
    float s = 0.f;
    for (int i = t; i < N_EDGES; i += 256) {
        float v = expf(row[i] - mx);
        row[i] = v;
        s += v;
    }
#pragma unroll
    for (int o = 32; o > 0; o >>= 1) s += __shfl_xor(s, o, 64);
    if ((t & 63) == 0) reds[t >> 6] = s;
    __syncthreads();
    float inv = 1.0f / (reds[0] + reds[1] + reds[2] + reds[3]);
    for (int i = t; i < N_EDGES; i += 256) row[i] *= inv;
}

// ---------- generic 128x128 bf16 MFMA GEMM, both operands k-contiguous ----------
// C[m][n] = sum_k A[m][k] * BT[n][k]
// MODE 0: store bf16 row-major to outB (ldo), +bz offsets        (WhT = WbT @ xb^T)
// MODE 1: scale by ae[(m>>6)*4096 + n], store bf16 to outB       (mwT = WhbT @ HbT^T)
// MODE 2: store fp32 to d_out at [b= n>>9][m][n&511]             (out = Hb @ mwT^T)
template <int MODE>
__launch_bounds__(256)
__global__ void gemm_bt(const __bf16* __restrict__ A, const __bf16* __restrict__ BT,
                        int lda, int ldbt, int K,
                        __bf16* __restrict__ outB, int ldo,
                        float* __restrict__ outF,
                        const float* __restrict__ ae,
                        size_t btz, size_t otz) {
    __shared__ __align__(16) __bf16 As[128][72];
    __shared__ __align__(16) __bf16 Bs[128][72];
    int t = threadIdx.x;
    int bz = blockIdx.z;
    BT += (size_t)bz * btz;
    if (MODE == 0) outB += (size_t)bz * otz;
    size_t m0 = (size_t)blockIdx.y * 128;
    size_t n0 = (size_t)blockIdx.x * 128;

    int lane = t & 63, wv = t >> 6;
    int wm = (wv & 1) * 64, wn = (wv >> 1) * 64;
    int lr = lane & 15, quad = lane >> 4;
    int sr = t >> 3, sch = (t & 7) * 8;  // staging: row 0..31, chunk col

    f32x4 acc[4][4] = {};

    for (int k0 = 0; k0 < K; k0 += 64) {
        __syncthreads();
#pragma unroll
        for (int p = 0; p < 4; ++p) {
            *(uint4*)&As[p * 32 + sr][sch] =
                *(const uint4*)&A[(m0 + p * 32 + sr) * (size_t)lda + k0 + sch];
            *(uint4*)&Bs[p * 32 + sr][sch] =
                *(const uint4*)&BT[(n0 + p * 32 + sr) * (size_t)ldbt + k0 + sch];
        }
        __syncthreads();
#pragma unroll
        for (int ks = 0; ks < 64; ks += 32) {
            bf16x8 af[4], bfr[4];
#pragma unroll
            for (int i = 0; i < 4; ++i)
                af[i] = *(const bf16x8*)&As[wm + i * 16 + lr][ks + quad * 8];
#pragma unroll
            for (int j = 0; j < 4; ++j)
                bfr[j] = *(const bf16x8*)&Bs[wn + j * 16 + lr][ks + quad * 8];
#pragma unroll
            for (int i = 0; i < 4; ++i)
#pragma unroll
                for (int j = 0; j < 4; ++j)
                    acc[i][j] = __builtin_amdgcn_mfma_f32_16x16x32_bf16(
                        af[i], bfr[j], acc[i][j], 0, 0, 0);
        }
    }

#pragma unroll
    for (int i = 0; i < 4; ++i)
#pragma unroll
        for (int j = 0; j < 4; ++j)
#pragma unroll
            for (int rg = 0; rg < 4; ++rg) {
                int gm = (int)m0 + wm + i * 16 + quad * 4 + rg;
                int gc = (int)n0 + wn + j * 16 + lr;
                float v = acc[i][j][rg];
                if (MODE == 0) {
                    outB[(size_t)gm * ldo + gc] = (__bf16)v;
                } else if (MODE == 1) {
                    float aev = ae[(size_t)(gm >> 6) * N_EDGES + gc];
                    outB[(size_t)gm * ldo + gc] = (__bf16)(v * aev);
                } else {
                    outF[(size_t)(gc >> 9) * ((size_t)N_NODES * HDIM) +
                         (size_t)gm * HDIM + (gc & 511)] = v;
                }
            }
}

extern "C" void kernel_launch(void* const* d_in, const int* in_sizes, int n_in,
                              void* d_out, int out_size, void* d_ws, size_t ws_size,
                              hipStream_t stream) {
    const float* x = (const float*)d_in[0];
    const float* H = (const float*)d_in[1];
    const float* W = (const float*)d_in[2];
    const float* a = (const float*)d_in[3];
    float* out = (float*)d_out;

    // workspace carve-up (~169 MB)
    char* p = (char*)d_ws;
    __bf16* Hb   = (__bf16*)p; p += (size_t)N_NODES * N_EDGES * 2;   // 67.1 MB
    __bf16* HbT  = (__bf16*)p; p += (size_t)N_EDGES * N_NODES * 2;   // 67.1 MB
    __bf16* xb   = (__bf16*)p; p += (size_t)BATCH * N_NODES * F_INS * 2; // 8.4 MB
    __bf16* WbT  = (__bf16*)p; p += (size_t)HDIM * F_INS * 2;        // 0.26 MB
    __bf16* WhbT = (__bf16*)p; p += (size_t)CCOMB * N_NODES * 2;     // 16.8 MB
    __bf16* mwT  = (__bf16*)p; p += (size_t)CCOMB * N_EDGES * 2;     // 8.4 MB
    float*  Wa   = (float*)p;  p += (size_t)F_INS * HEADS * 4;
    float*  av   = (float*)p;  p += (size_t)BATCH * N_NODES * HEADS * 4;
    float*  ae   = (float*)p;  p += (size_t)16 * N_EDGES * 4;        // logits -> softmax in place

    convert_H_kernel<<<dim3(N_EDGES / 32, N_NODES / 32), 256, 0, stream>>>(H, Hb, HbT);
    cvt_x_kernel<<<dim3(BATCH * N_NODES * F_INS / 4 / 256), 256, 0, stream>>>(
        x, xb, BATCH * N_NODES * F_INS / 4);
    wbt_kernel<<<dim3(HDIM * F_INS / 256), 256, 0, stream>>>(W, WbT);
    wa_kernel<<<dim3(8), 256, 0, stream>>>(W, a, Wa);
    av_kernel<<<dim3(BATCH * N_NODES / 32), 256, 0, stream>>>(x, Wa, av);

    // WhT[b*512+c][n] = sum_f WbT[c][f] * xb[b][n][f]
    gemm_bt<0><<<dim3(64, 4, 2), 256, 0, stream>>>(
        WbT, xb, F_INS, F_INS, F_INS, WhbT, N_NODES, nullptr, nullptr,
        (size_t)N_NODES * F_INS, (size_t)HDIM * N_NODES);

    hipMemsetAsync(ae, 0, (size_t)16 * N_EDGES * 4, stream);
    logits_kernel<<<dim3(16, 16), 256, 0, stream>>>(H, av, ae);
    softmax_kernel<<<dim3(16), 256, 0, stream>>>(ae);

    // mwT[c][e] = ae[bh][e] * sum_n WhbT[c][n] * HbT[e][n]
    gemm_bt<1><<<dim3(32, 8, 1), 256, 0, stream>>>(
        WhbT, HbT, N_NODES, N_NODES, N_NODES, mwT, N_EDGES, nullptr, ae, 0, 0);

    // out[b][n][hd] = sum_e Hb[n][e] * mwT[b*512+hd][e]
    gemm_bt<2><<<dim3(8, 64, 1), 256, 0, stream>>>(
        Hb, mwT, N_EDGES, N_EDGES, N_EDGES, nullptr, 0, out, nullptr, 0, 0);
}